// Round 4
// baseline (304.883 us; speedup 1.0000x reference)
//
#include <hip/hip_runtime.h>
#include <hip/hip_bf16.h>
#include <stdint.h>

typedef __bf16 bf16;
typedef bf16 bf16x4 __attribute__((ext_vector_type(4)));
typedef bf16 bf16x8 __attribute__((ext_vector_type(8)));
typedef float f32x4 __attribute__((ext_vector_type(4)));
typedef float fv4 __attribute__((ext_vector_type(4)));   // native clang vector for nontemporal builtins

#define FIN   128
#define FOUT  128
#define FANIN 640
#define BM    128

// ---------------- convert fp32 -> bf16 (x and W), non-temporal reads ----------------
__global__ __launch_bounds__(256)
void convert_kernel(const float* __restrict__ x, const float* __restrict__ W,
                    bf16* __restrict__ xb, bf16* __restrict__ wb,
                    long nx4, long ntot4)
{
    long i = (long)blockIdx.x * 256 + threadIdx.x;   // float4 index
    if (i >= ntot4) return;
    fv4 v;
    bf16* dst;
    if (i < nx4) { v = __builtin_nontemporal_load((const fv4*)x + i); dst = xb + i * 4; }
    else         { long k = i - nx4;
                   v = __builtin_nontemporal_load((const fv4*)W + k); dst = wb + k * 4; }
    bf16x4 h = { (bf16)v.x, (bf16)v.y, (bf16)v.z, (bf16)v.w };
    *(bf16x4*)dst = h;
}

// ---------------- gather-GEMM v5: ZERO LDS, zero barriers, register-direct fragments --------
// Rounds 0-3 post-mortem: every LDS-staged variant is stuck in the {pipeline depth vs LDS
// size vs barrier tail-latency} triangle — each block-wide vmcnt(0)+s_barrier makes 256
// threads wait on the slowest of ~32 random-row gathers, every chunk (per-CU arithmetic:
// ~12K cy per chunk-phase vs ~300 cy of MFMA).
// v5 observation: the MFMA A-fragment is natively gatherable — lane l16 of a[mi] needs 16
// contiguous bytes from row gsel[mi][j] at col s*64+quad*16 = one global_load_dwordx4.
// So: no LDS, no barriers; each wave runs K=640 register-only. Compiler freely hoists
// loads across MFMAs (no barrier blocks motion); waves slide independently (no convoy);
// occupancy bounded by VGPR only. Per-slot row reuse (4 steps share 16 rows) keeps L1/L2
// locality. Slot loop fully unrolled (rule #20: runtime-indexed gsel would go to scratch).
// NO launch_bounds reg-cap (round-2 lesson: a cap turns pressure into HBM spill traffic).
__global__ __launch_bounds__(256)
void mcc_mfma(const bf16* __restrict__ xb, const int* __restrict__ nbr,
              const bf16* __restrict__ wb, const float* __restrict__ bias,
              float* __restrict__ out, int N)
{
    const int tid  = threadIdx.x;
    const int wave = tid >> 6;
    const int lane = tid & 63;
    const int quad = lane >> 4;
    const int l16  = lane & 15;
    const int wr   = wave >> 1;      // wave row 0..1 (64 out-rows each)
    const int wc   = wave & 1;       // wave col 0..1 (64 out-cols each)
    const int m0   = blockIdx.x * BM;

    // per-lane gather node ids for this lane's fragment rows: gsel[mi][slot]
    int gsel[4][5];
    #pragma unroll
    for (int mi = 0; mi < 4; ++mi) {
        int node = m0 + wr * 64 + mi * 16 + l16;
        node = node < N ? node : N - 1;
        gsel[mi][0] = node;
        #pragma unroll
        for (int jj = 1; jj < 5; ++jj)
            gsel[mi][jj] = nbr[(long)node * 4 + (jj - 1)];
    }

    const char* xq = (const char*)xb + quad * 16;   // per-lane k-phase base
    const char* wq = (const char*)wb + quad * 16;
    int boff[4];
    #pragma unroll
    for (int ni = 0; ni < 4; ++ni)
        boff[ni] = (wc * 64 + ni * 16 + l16) * (FANIN * 2);

    f32x4 acc[4][4] = {};

    #pragma unroll
    for (int j = 0; j < 5; ++j) {                   // gather slot (self + 4 neighbors)
        const char* pA[4];
        #pragma unroll
        for (int mi = 0; mi < 4; ++mi)
            pA[mi] = xq + ((long)gsel[mi][j] << 8);

        #pragma unroll
        for (int s = 0; s < 4; ++s) {               // K-step of 32 within the slot
            bf16x8 a[4], b[4];
            #pragma unroll
            for (int mi = 0; mi < 4; ++mi)
                a[mi] = *(const bf16x8*)(pA[mi] + s * 64);
            #pragma unroll
            for (int ni = 0; ni < 4; ++ni)
                b[ni] = *(const bf16x8*)(wq + boff[ni] + j * 256 + s * 64);

            __builtin_amdgcn_s_setprio(1);
            #pragma unroll
            for (int mi = 0; mi < 4; ++mi)
                #pragma unroll
                for (int ni = 0; ni < 4; ++ni)
                    acc[mi][ni] = __builtin_amdgcn_mfma_f32_16x16x32_bf16(
                                      a[mi], b[ni], acc[mi][ni], 0, 0, 0);
            __builtin_amdgcn_s_setprio(0);
        }
    }

    // ---- epilogue: C layout col=lane&15, row=quad*4+reg; non-temporal stores ----
    float bv[4];
    #pragma unroll
    for (int ni = 0; ni < 4; ++ni) bv[ni] = bias[wc * 64 + ni * 16 + l16];

    #pragma unroll
    for (int mi = 0; mi < 4; ++mi) {
        #pragma unroll
        for (int r = 0; r < 4; ++r) {
            int row = m0 + wr * 64 + mi * 16 + quad * 4 + r;
            if (row < N) {
                #pragma unroll
                for (int ni = 0; ni < 4; ++ni) {
                    int n = wc * 64 + ni * 16 + l16;
                    __builtin_nontemporal_store(acc[mi][ni][r] + bv[ni],
                                                &out[(long)row * FOUT + n]);
                }
            }
        }
    }
}

// ---------------- round-1 fallback (used only if ws_size too small) ----------------
#define FBM 64
#define LDA 136
__global__ __launch_bounds__(256)
void mcc_fallback(const float* __restrict__ x, const int* __restrict__ nbr,
                  const float* __restrict__ W, const float* __restrict__ bias,
                  float* __restrict__ out, int N)
{
    __shared__ __align__(16) bf16 As[FBM][LDA];
    __shared__ __align__(16) bf16 Bs[FOUT][LDA];
    const int tid = threadIdx.x;
    const int m0 = blockIdx.x * FBM;
    const int wave = tid >> 6, lane = tid & 63, quad = lane >> 4, l16 = lane & 15;
    f32x4 acc[8] = {};
    const int arow = tid >> 2, asub = tid & 3, brow = tid >> 1, bhalf = tid & 1;
    for (int j = 0; j < 5; ++j) {
        {
            const float4* src = (const float4*)(W + (long)brow * FANIN + j * FIN + bhalf * 64);
            bf16* dst = &Bs[brow][bhalf * 64];
            #pragma unroll
            for (int i = 0; i < 16; ++i) {
                float4 v = src[i];
                dst[i*4+0]=(bf16)v.x; dst[i*4+1]=(bf16)v.y; dst[i*4+2]=(bf16)v.z; dst[i*4+3]=(bf16)v.w;
            }
        }
        {
            int node = m0 + arow; int nc = node < N ? node : N - 1;
            long long g = (j == 0) ? (long long)nc : (long long)nbr[(long long)nc * 4 + (j - 1)];
            const float4* src = (const float4*)(x + g * FIN);
            #pragma unroll
            for (int i = 0; i < 8; ++i) {
                int c4 = asub + i * 4;
                float4 v = src[c4];
                bf16* dst = &As[arow][c4 * 4];
                dst[0]=(bf16)v.x; dst[1]=(bf16)v.y; dst[2]=(bf16)v.z; dst[3]=(bf16)v.w;
            }
        }
        __syncthreads();
        #pragma unroll
        for (int kk = 0; kk < 4; ++kk) {
            bf16x8 a = *(const bf16x8*)&As[wave * 16 + l16][kk * 32 + quad * 8];
            #pragma unroll
            for (int nt = 0; nt < 8; ++nt) {
                bf16x8 b = *(const bf16x8*)&Bs[nt * 16 + l16][kk * 32 + quad * 8];
                acc[nt] = __builtin_amdgcn_mfma_f32_16x16x32_bf16(a, b, acc[nt], 0, 0, 0);
            }
        }
        __syncthreads();
    }
    const int m_local = wave * 16 + quad * 4;
    #pragma unroll
    for (int nt = 0; nt < 8; ++nt) {
        int n = nt * 16 + l16;
        float bvv = bias[n];
        #pragma unroll
        for (int r = 0; r < 4; ++r) {
            int node = m0 + m_local + r;
            if (node < N) out[(long)node * FOUT + n] = acc[nt][r] + bvv;
        }
    }
}

extern "C" void kernel_launch(void* const* d_in, const int* in_sizes, int n_in,
                              void* d_out, int out_size, void* d_ws, size_t ws_size,
                              hipStream_t stream) {
    const float* x    = (const float*)d_in[0];
    const int*   nbr  = (const int*)d_in[1];
    const float* W    = (const float*)d_in[2];
    const float* bias = (const float*)d_in[3];
    float* out = (float*)d_out;

    int N = in_sizes[0] / FIN;                              // 200000
    size_t xb_bytes = (size_t)N * FIN * sizeof(bf16);       // 51.2 MB
    size_t wb_bytes = (size_t)FOUT * FANIN * sizeof(bf16);  // 160 KB

    if (ws_size >= xb_bytes + wb_bytes) {
        bf16* xb = (bf16*)d_ws;
        bf16* wb = (bf16*)((char*)d_ws + xb_bytes);
        long nx4   = (long)N * FIN / 4;
        long ntot4 = nx4 + (long)FOUT * FANIN / 4;
        int cgrid = (int)((ntot4 + 255) / 256);
        convert_kernel<<<cgrid, 256, 0, stream>>>(x, W, xb, wb, nx4, ntot4);
        int grid = (N + BM - 1) / BM;                       // 1563
        mcc_mfma<<<grid, 256, 0, stream>>>(xb, nbr, wb, bias, out, N);
    } else {
        int grid = (N + FBM - 1) / FBM;
        mcc_fallback<<<grid, 256, 0, stream>>>(x, nbr, W, bias, out, N);
    }
}

// Round 5
// 231.231 us; speedup vs baseline: 1.3185x; 1.3185x over previous
//
#include <hip/hip_runtime.h>
#include <hip/hip_bf16.h>
#include <stdint.h>

typedef __bf16 bf16;
typedef bf16 bf16x4 __attribute__((ext_vector_type(4)));
typedef bf16 bf16x8 __attribute__((ext_vector_type(8)));
typedef float f32x4 __attribute__((ext_vector_type(4)));
typedef float fv4 __attribute__((ext_vector_type(4)));   // native clang vector for nontemporal builtins

#define FIN   128
#define FOUT  128
#define FANIN 640
#define BM    128
#define BK    64      // K sub-chunk (bf16 elems); A,B tiles 16KB each, single-buffered = 32KB

// ---------------- convert fp32 -> bf16 (x and W), non-temporal reads ----------------
__global__ __launch_bounds__(256)
void convert_kernel(const float* __restrict__ x, const float* __restrict__ W,
                    bf16* __restrict__ xb, bf16* __restrict__ wb,
                    long nx4, long ntot4)
{
    long i = (long)blockIdx.x * 256 + threadIdx.x;   // float4 index
    if (i >= ntot4) return;
    fv4 v;
    bf16* dst;
    if (i < nx4) { v = __builtin_nontemporal_load((const fv4*)x + i); dst = xb + i * 4; }
    else         { long k = i - nx4;
                   v = __builtin_nontemporal_load((const fv4*)W + k); dst = wb + k * 4; }
    bf16x4 h = { (bf16)v.x, (bf16)v.y, (bf16)v.z, (bf16)v.w };
    *(bf16x4*)dst = h;
}

// ---------------- gather-GEMM v6: T14 reg-staged pipeline, single 32KB buffer ----------------
// Lessons: r1 (64KB dbuf) kills occupancy; r2 (operands from global) spills; r3 (BK=32)
// bank-conflicts + too-short prefetch; r4 (per-lane fragment gather) dies on 16-cache-line
// address divergence per VMEM instruction. r0's transport geometry (8 lanes/row, 2 rows per
// 16B-wide instr, pre-swizzled global src, linear LDS) was right — only its prefetch
// distance (0) was wrong. v6 keeps the geometry byte-for-byte but splits staging:
//   issue chunk c+1's 8 global_load_dwordx4 into REGS during chunk c's MFMAs,
//   then next iteration: WAR barrier -> vmcnt(0) (loads are a full phase old -> cheap)
//   -> 8 ds_write_b128 -> lgkmcnt(0) -> barrier -> compute.
// Single A+B buffer keeps LDS at 32KB (r0 occupancy). Barriers order only fast LDS ops;
// no fresh-gather vmcnt drain anywhere in the loop.
__global__ __launch_bounds__(256)
void mcc_mfma(const bf16* __restrict__ xb, const int* __restrict__ nbr,
              const bf16* __restrict__ wb, const float* __restrict__ bias,
              float* __restrict__ out, int N)
{
    __shared__ __align__(16) bf16 Asm[BM][BK];     // 16 KB
    __shared__ __align__(16) bf16 Bsm[FOUT][BK];   // 16 KB

    const int tid  = threadIdx.x;
    const int wave = tid >> 6;
    const int lane = tid & 63;
    const int quad = lane >> 4;
    const int l16  = lane & 15;
    const int wr   = wave >> 1;      // wave row 0..1 (64 out-rows each)
    const int wc   = wave & 1;       // wave col 0..1 (64 out-cols each)
    const int m0   = blockIdx.x * BM;

    const int r8 = lane >> 3;        // row-within-staging-group 0..7
    const int c8 = lane & 7;         // 16B chunk 0..7
    const int sw = (c8 ^ r8) << 4;   // swizzled chunk byte offset (baked into global src)

    // preload gather row ids into VGPRs: gsel[i][j], i = staging group, j = slot
    int gsel[4][5];
    #pragma unroll
    for (int i = 0; i < 4; ++i) {
        int tr   = wave * 32 + i * 8 + r8;
        int node = m0 + tr;
        node = node < N ? node : N - 1;
        gsel[i][0] = node;
        #pragma unroll
        for (int jj = 1; jj < 5; ++jj)
            gsel[i][jj] = nbr[(long)node * 4 + (jj - 1)];   // 8 lanes share addr (broadcast)
    }
    // drain nbr loads so the loop-time vmem queue holds only staging loads
    asm volatile("s_waitcnt vmcnt(0)" ::: "memory");

    f32x4 acc[4][4] = {};
    bf16x8 gA[4], gB[4];             // in-flight staging registers (32 VGPRs)

    // issue chunk k's 8 staging loads (same addresses r0's async16 used)
    #define LOADS(k) do {                                                                  \
        const int j_ = (k) >> 1, h_ = (k) & 1;                                             \
        _Pragma("unroll")                                                                  \
        for (int i = 0; i < 4; ++i)                                                        \
            gA[i] = *(const bf16x8*)((const char*)xb + ((long)gsel[i][j_] << 8)            \
                                     + h_ * 128 + sw);                                     \
        _Pragma("unroll")                                                                  \
        for (int i = 0; i < 4; ++i) {                                                      \
            int br_ = wave * 32 + i * 8 + r8;                                              \
            gB[i] = *(const bf16x8*)((const char*)wb + (long)br_ * (FANIN * 2)             \
                                     + j_ * 256 + h_ * 128 + sw);                          \
        }                                                                                  \
    } while (0)

    LOADS(0);

    #pragma unroll
    for (int c = 0; c < 10; ++c) {
        // WAR: all waves consumed chunk c-1 (their ds_reads completed before their MFMAs)
        __builtin_amdgcn_s_barrier();
        asm volatile("" ::: "memory");

        // staging regs arrived (issued one full compute phase ago; cheap wait)
        asm volatile("s_waitcnt vmcnt(0)" ::: "memory");
        #pragma unroll
        for (int i = 0; i < 4; ++i)
            *(bf16x8*)((char*)&Asm[wave * 32 + i * 8][0] + lane * 16) = gA[i];
        #pragma unroll
        for (int i = 0; i < 4; ++i)
            *(bf16x8*)((char*)&Bsm[wave * 32 + i * 8][0] + lane * 16) = gB[i];
        asm volatile("s_waitcnt lgkmcnt(0)" ::: "memory");
        __builtin_amdgcn_s_barrier();               // tile visible to all waves
        asm volatile("" ::: "memory");

        // issue next chunk's staging loads; they fly across the whole compute phase
        if (c < 9) LOADS(c + 1);

        #pragma unroll
        for (int s = 0; s < 2; ++s) {
            bf16x8 a[4], b[4];
            #pragma unroll
            for (int mi = 0; mi < 4; ++mi) {
                int ar = wr * 64 + mi * 16 + l16;
                a[mi] = *(const bf16x8*)&Asm[ar][(((s * 4 + quad) ^ (l16 & 7)) << 3)];
            }
            #pragma unroll
            for (int ni = 0; ni < 4; ++ni) {
                int br = wc * 64 + ni * 16 + l16;
                b[ni] = *(const bf16x8*)&Bsm[br][(((s * 4 + quad) ^ (l16 & 7)) << 3)];
            }
            __builtin_amdgcn_s_setprio(1);
            #pragma unroll
            for (int mi = 0; mi < 4; ++mi)
                #pragma unroll
                for (int ni = 0; ni < 4; ++ni)
                    acc[mi][ni] = __builtin_amdgcn_mfma_f32_16x16x32_bf16(
                                      a[mi], b[ni], acc[mi][ni], 0, 0, 0);
            __builtin_amdgcn_s_setprio(0);
        }
    }
    #undef LOADS

    // ---- epilogue: C layout col=lane&15, row=quad*4+reg; non-temporal stores ----
    float bv[4];
    #pragma unroll
    for (int ni = 0; ni < 4; ++ni) bv[ni] = bias[wc * 64 + ni * 16 + l16];

    #pragma unroll
    for (int mi = 0; mi < 4; ++mi) {
        #pragma unroll
        for (int r = 0; r < 4; ++r) {
            int row = m0 + wr * 64 + mi * 16 + quad * 4 + r;
            if (row < N) {
                #pragma unroll
                for (int ni = 0; ni < 4; ++ni) {
                    int n = wc * 64 + ni * 16 + l16;
                    __builtin_nontemporal_store(acc[mi][ni][r] + bv[ni],
                                                &out[(long)row * FOUT + n]);
                }
            }
        }
    }
}

// ---------------- round-1 fallback (used only if ws_size too small) ----------------
#define FBM 64
#define LDA 136
__global__ __launch_bounds__(256)
void mcc_fallback(const float* __restrict__ x, const int* __restrict__ nbr,
                  const float* __restrict__ W, const float* __restrict__ bias,
                  float* __restrict__ out, int N)
{
    __shared__ __align__(16) bf16 As[FBM][LDA];
    __shared__ __align__(16) bf16 Bs[FOUT][LDA];
    const int tid = threadIdx.x;
    const int m0 = blockIdx.x * FBM;
    const int wave = tid >> 6, lane = tid & 63, quad = lane >> 4, l16 = lane & 15;
    f32x4 acc[8] = {};
    const int arow = tid >> 2, asub = tid & 3, brow = tid >> 1, bhalf = tid & 1;
    for (int j = 0; j < 5; ++j) {
        {
            const float4* src = (const float4*)(W + (long)brow * FANIN + j * FIN + bhalf * 64);
            bf16* dst = &Bs[brow][bhalf * 64];
            #pragma unroll
            for (int i = 0; i < 16; ++i) {
                float4 v = src[i];
                dst[i*4+0]=(bf16)v.x; dst[i*4+1]=(bf16)v.y; dst[i*4+2]=(bf16)v.z; dst[i*4+3]=(bf16)v.w;
            }
        }
        {
            int node = m0 + arow; int nc = node < N ? node : N - 1;
            long long g = (j == 0) ? (long long)nc : (long long)nbr[(long long)nc * 4 + (j - 1)];
            const float4* src = (const float4*)(x + g * FIN);
            #pragma unroll
            for (int i = 0; i < 8; ++i) {
                int c4 = asub + i * 4;
                float4 v = src[c4];
                bf16* dst = &As[arow][c4 * 4];
                dst[0]=(bf16)v.x; dst[1]=(bf16)v.y; dst[2]=(bf16)v.z; dst[3]=(bf16)v.w;
            }
        }
        __syncthreads();
        #pragma unroll
        for (int kk = 0; kk < 4; ++kk) {
            bf16x8 a = *(const bf16x8*)&As[wave * 16 + l16][kk * 32 + quad * 8];
            #pragma unroll
            for (int nt = 0; nt < 8; ++nt) {
                bf16x8 b = *(const bf16x8*)&Bs[nt * 16 + l16][kk * 32 + quad * 8];
                acc[nt] = __builtin_amdgcn_mfma_f32_16x16x32_bf16(a, b, acc[nt], 0, 0, 0);
            }
        }
        __syncthreads();
    }
    const int m_local = wave * 16 + quad * 4;
    #pragma unroll
    for (int nt = 0; nt < 8; ++nt) {
        int n = nt * 16 + l16;
        float bvv = bias[n];
        #pragma unroll
        for (int r = 0; r < 4; ++r) {
            int node = m0 + m_local + r;
            if (node < N) out[(long)node * FOUT + n] = acc[nt][r] + bvv;
        }
    }
}

extern "C" void kernel_launch(void* const* d_in, const int* in_sizes, int n_in,
                              void* d_out, int out_size, void* d_ws, size_t ws_size,
                              hipStream_t stream) {
    const float* x    = (const float*)d_in[0];
    const int*   nbr  = (const int*)d_in[1];
    const float* W    = (const float*)d_in[2];
    const float* bias = (const float*)d_in[3];
    float* out = (float*)d_out;

    int N = in_sizes[0] / FIN;                              // 200000
    size_t xb_bytes = (size_t)N * FIN * sizeof(bf16);       // 51.2 MB
    size_t wb_bytes = (size_t)FOUT * FANIN * sizeof(bf16);  // 160 KB

    if (ws_size >= xb_bytes + wb_bytes) {
        bf16* xb = (bf16*)d_ws;
        bf16* wb = (bf16*)((char*)d_ws + xb_bytes);
        long nx4   = (long)N * FIN / 4;
        long ntot4 = nx4 + (long)FOUT * FANIN / 4;
        int cgrid = (int)((ntot4 + 255) / 256);
        convert_kernel<<<cgrid, 256, 0, stream>>>(x, W, xb, wb, nx4, ntot4);
        int grid = (N + BM - 1) / BM;                       // 1563
        mcc_mfma<<<grid, 256, 0, stream>>>(xb, nbr, wb, bias, out, N);
    } else {
        int grid = (N + FBM - 1) / FBM;
        mcc_fallback<<<grid, 256, 0, stream>>>(x, nbr, W, bias, out, N);
    }
}